// Round 6
// baseline (1083.320 us; speedup 1.0000x reference)
//
#include <hip/hip_runtime.h>
#include <hip/hip_bf16.h>

using bf16 = __hip_bfloat16;

typedef short bf16x8 __attribute__((ext_vector_type(8)));
typedef float f32x4  __attribute__((ext_vector_type(4)));

__device__ __forceinline__ f32x4 ld4u(const float* p) {
    f32x4 r;
    __builtin_memcpy(&r, p, 16);   // 4B-aligned dwordx4
    return r;
}

__device__ __forceinline__ bf16x8 pack8(f32x4 a, f32x4 b) {
    union { bf16x8 v; __hip_bfloat162 h2[4]; } u;
    u.h2[0] = __float22bfloat162_rn(make_float2(a.x, a.y));
    u.h2[1] = __float22bfloat162_rn(make_float2(a.z, a.w));
    u.h2[2] = __float22bfloat162_rn(make_float2(b.x, b.y));
    u.h2[3] = __float22bfloat162_rn(make_float2(b.z, b.w));
    return u.v;
}

// Pack W[co][ci][dw][dx][dy][dz] into per-lane MFMA fragment order (validated r5):
// frag elem (lane l, e): i = l&15 = co*4+dy ; k = (l>>4)*8 + e -> (ci,dw,dx,dz) dz-fastest.
// Same layout serves as the A-operand (weights) of mfma(A=W, B=X, C).
__global__ __launch_bounds__(64)
void pack_weights(const float* __restrict__ w1, const float* __restrict__ w2,
                  const float* __restrict__ w3, ushort* __restrict__ wp)
{
    const int L = blockIdx.x, l = threadIdx.x;
    const int CIN  = (L == 0) ? 1 : 3;
    const int COUT = (L == 2) ? 4 : 3;
    const int NSTEP = (L == 0) ? 2 : 6;
    const float* w = (L == 0) ? w1 : (L == 1) ? w2 : w3;
    ushort* dst = wp + ((L == 0) ? 0 : (L == 1) ? 1024 : 4096);

    const int n = l & 15, g = l >> 4;
    const int co = n >> 2, dy = n & 3;
    for (int s = 0; s < NSTEP; ++s)
        for (int e = 0; e < 8; ++e) {
            int k = s * 32 + g * 8 + e;
            int dz = k & 3, dx = (k >> 2) & 3, dw = (k >> 4) & 3, ci = k >> 6;
            float v = 0.f;
            if (co < COUT) v = w[((((co * CIN + ci) * 4 + dw) * 4 + dx) * 4 + dy) * 4 + dz];
            bf16 h = __float2bfloat16(v);
            ushort us; __builtin_memcpy(&us, &h, 2);
            dst[(s * 64 + l) * 8 + e] = us;
        }
}

// Implicit-GEMM 4D conv, MFMA 16x16x32 bf16, weights as A (rows = co*4+dy),
// input as B (cols = positions r = oz*SIN + iy, iy-fastest). The dy-reduction
// out[co][oy][oz] = sum_dy Z[(co,dy)][(oz,oy+dy)] becomes an in-register
// shuffle gather: lane (g,n) of tile t sums reg j of lanes n+j (tiles t/t+1).
// Block = 4 waves = 4 consecutive units (b,ow,ox). No LDS, no barriers.
template<int CIN, int COUT, int SIN>
__global__ __launch_bounds__(256, 2)
void conv4d_mfma(const float* __restrict__ in, const ushort* __restrict__ wp,
                 const float* __restrict__ bias, float* __restrict__ out)
{
    constexpr int SOUT = SIN - 3;
    constexpr int NSTEP = CIN * 2;           // CIN*64 / 32
    constexpr int POS = SOUT * SIN;          // (oz, iy) positions, iy fastest
    constexpr int MT = (POS + 15) / 16;
    constexpr int S2 = SIN * SIN, S3 = SIN * S2, S4 = SIN * S3;

    const int l   = threadIdx.x & 63;
    const int wid = threadIdx.x >> 6;
    const int u   = blockIdx.x * 4 + wid;
    const int ox = u % SOUT, ow = (u / SOUT) % SOUT, b = u / (SOUT * SOUT);
    const int n = l & 15, g = l >> 4;

    // A-operand: weight fragments (persistent, 16B aligned)
    bf16x8 wf[NSTEP];
    #pragma unroll
    for (int s = 0; s < NSTEP; ++s)
        wf[s] = *reinterpret_cast<const bf16x8*>(wp + (s * 64 + l) * 8);

    // per-lane position offsets (clamped pad positions stay in-bounds)
    int aoff[MT];
    #pragma unroll
    for (int t = 0; t < MT; ++t) {
        int r = t * 16 + n; if (r > POS - 1) r = POS - 1;
        int iy = r % SIN, oz = r / SIN;
        aoff[t] = iy * SIN + oz;
    }

    // per-lane slab pointers per k-step: k8 = s*32+g*8 -> (ci,dw,dxb)
    const float* pbase = in + (size_t)b * CIN * S4 + ow * S3 + ox * S2;
    const float* ps[NSTEP];
    #pragma unroll
    for (int s = 0; s < NSTEP; ++s) {
        int k8 = s * 32 + g * 8;
        int dxb = (k8 >> 2) & 3, dw = (k8 >> 4) & 3, ci = k8 >> 6;
        ps[s] = pbase + ci * S4 + dw * S3 + dxb * S2;
    }

    f32x4 acc[MT];
    #pragma unroll
    for (int t = 0; t < MT; ++t) acc[t] = 0;

    // s-outer / t-inner: MT independent load->pack->mfma streams per step
    #pragma unroll
    for (int s = 0; s < NSTEP; ++s)
        #pragma unroll
        for (int t = 0; t < MT; ++t) {
            f32x4 va = ld4u(ps[s] + aoff[t]);
            f32x4 vb = ld4u(ps[s] + S2 + aoff[t]);
            acc[t] = __builtin_amdgcn_mfma_f32_16x16x32_bf16(wf[s], pack8(va, vb), acc[t], 0, 0, 0);
        }

    // In-register dy-reduce epilogue: v(r) = sum_j Z[reg j](lane n+j)
    const float bb = bias[g < COUT ? g : 0];
    #pragma unroll
    for (int t = 0; t < MT; ++t) {
        float v = acc[t][0];
        #pragma unroll
        for (int j = 1; j < 4; ++j) {
            const int sl = (l & 48) | ((n + j) & 15);
            float a1 = __shfl(acc[t][j], sl, 64);
            float a2 = __shfl(acc[(t + 1 < MT) ? t + 1 : t][j], sl, 64);
            v += (n + j < 16) ? a1 : a2;
        }
        int r = t * 16 + n;
        if (r < POS && g < COUT) {
            int iy = r % SIN, oz = r / SIN;
            if (iy < SOUT) {   // oy = iy
                float o = v + bb; o = o > 0.f ? o : 0.f;
                out[((((size_t)(b * COUT + g) * SOUT + ow) * SOUT + ox) * SOUT + iy) * SOUT + oz] = o;
            }
        }
    }
}

// ---- fp32 direct conv (conv4/conv5 + fallback tiers) ----
template<int CIN, int COUT, int SIN, int K>
__global__ __launch_bounds__(256)
void conv4d_relu(const float* __restrict__ in, const float* __restrict__ w,
                 const float* __restrict__ bias, float* __restrict__ out, int total)
{
    constexpr int SOUT = SIN - K + 1;
    constexpr int K4 = K * K * K * K;

    const int t = blockIdx.x * 256 + threadIdx.x;
    if (t >= total) return;
    const int oz = t % SOUT;
    const int ox = (t / SOUT) % SOUT;
    const int ow = (t / (SOUT * SOUT)) % SOUT;
    const int b  = t / (SOUT * SOUT * SOUT);

    float acc[COUT][SOUT];
    #pragma unroll
    for (int co = 0; co < COUT; ++co)
        #pragma unroll
        for (int oy = 0; oy < SOUT; ++oy) acc[co][oy] = 0.f;

    for (int ci = 0; ci < CIN; ++ci)
    for (int dw = 0; dw < K; ++dw)
    for (int dx = 0; dx < K; ++dx) {
        float wv[COUT][K][K];
        const int wbase = ((ci * K + dw) * K + dx) * K * K;
        #pragma unroll
        for (int co = 0; co < COUT; ++co)
            #pragma unroll
            for (int dy = 0; dy < K; ++dy)
                #pragma unroll
                for (int dz = 0; dz < K; ++dz)
                    wv[co][dy][dz] = w[co * (CIN * K4) + wbase + dy * K + dz];

        const float* col = in
            + ((((long)(b * CIN + ci) * SIN + (ow + dw)) * SIN + (ox + dx)) * SIN) * (long)SIN
            + oz;

        #pragma unroll
        for (int iy = 0; iy < SIN; ++iy) {
            float r[K];
            #pragma unroll
            for (int dz = 0; dz < K; ++dz) r[dz] = col[iy * SIN + dz];
            #pragma unroll
            for (int dy = 0; dy < K; ++dy) {
                if (iy - dy >= 0 && iy - dy < SOUT) {
                    #pragma unroll
                    for (int co = 0; co < COUT; ++co)
                        #pragma unroll
                        for (int dz = 0; dz < K; ++dz)
                            acc[co][iy - dy] = fmaf(r[dz], wv[co][dy][dz], acc[co][iy - dy]);
                }
            }
        }
    }

    #pragma unroll
    for (int co = 0; co < COUT; ++co) {
        const float bb = bias[co];
        float* op = out
            + ((((long)(b * COUT + co) * SOUT + ow) * SOUT + ox) * SOUT) * (long)SOUT
            + oz;
        #pragma unroll
        for (int oy = 0; oy < SOUT; ++oy) {
            float v = acc[co][oy] + bb;
            op[oy * SOUT] = v > 0.f ? v : 0.f;
        }
    }
}

// Fused dense1(1280->33, ReLU) + dense2(33->2) + softmax. One wave per batch item.
__global__ __launch_bounds__(64)
void dense_head(const float* __restrict__ h, const float* __restrict__ dw1,
                const float* __restrict__ db1, const float* __restrict__ dw2,
                const float* __restrict__ db2, float* __restrict__ out)
{
    __shared__ float hs[1280];
    __shared__ float gbuf[33];
    const int b = blockIdx.x, l = threadIdx.x;

    for (int i = l; i < 1280; i += 64) hs[i] = h[b * 1280 + i];
    __syncthreads();

    for (int j = 0; j < 33; ++j) {
        float a = 0.f;
        for (int k = l; k < 1280; k += 64) a += hs[k] * dw1[j * 1280 + k];
        #pragma unroll
        for (int off = 32; off > 0; off >>= 1) a += __shfl_down(a, off);
        if (l == 0) { float v = a + db1[j]; gbuf[j] = v > 0.f ? v : 0.f; }
    }
    __syncthreads();

    if (l == 0) {
        float l0 = db2[0], l1 = db2[1];
        for (int j = 0; j < 33; ++j) { l0 += gbuf[j] * dw2[j]; l1 += gbuf[j] * dw2[33 + j]; }
        float m = l0 > l1 ? l0 : l1;
        float e0 = expf(l0 - m), e1 = expf(l1 - m);
        float s = e0 + e1;
        out[b * 2 + 0] = e0 / s;
        out[b * 2 + 1] = e1 / s;
    }
}

extern "C" void kernel_launch(void* const* d_in, const int* in_sizes, int n_in,
                              void* d_out, int out_size, void* d_ws, size_t ws_size,
                              hipStream_t stream)
{
    const float* x   = (const float*)d_in[0];
    const float* w1  = (const float*)d_in[1];  const float* b1  = (const float*)d_in[2];
    const float* w2  = (const float*)d_in[3];  const float* b2  = (const float*)d_in[4];
    const float* w3  = (const float*)d_in[5];  const float* b3  = (const float*)d_in[6];
    const float* w4  = (const float*)d_in[7];  const float* b4  = (const float*)d_in[8];
    const float* w5  = (const float*)d_in[9];  const float* b5  = (const float*)d_in[10];
    const float* dw1 = (const float*)d_in[11]; const float* db1 = (const float*)d_in[12];
    const float* dw2 = (const float*)d_in[13]; const float* db2 = (const float*)d_in[14];
    float* outp = (float*)d_out;

    const size_t F1 = 256L * 3 * 15 * 15 * 15 * 15;  // 38,880,000
    const size_t F2 = 256L * 3 * 12 * 12 * 12 * 12;  // 15,925,248
    const size_t F3 = 256L * 4 * 9 * 9 * 9 * 9;      //  6,718,464
    const size_t F4 = 256L * 5 * 6 * 6 * 6 * 6;      //  1,658,880
    const size_t F5 = 256L * 5 * 4 * 4 * 4 * 4;      //    327,680
    const size_t WPB = 16384;

    char* base = (char*)d_ws;

    auto T4n = [](int nb){ return nb * 6 * 6 * 6; };
    auto T5n = [](int nb){ return nb * 4 * 4 * 4; };
    auto GB  = [](int th){ return (th + 255) / 256; };

    if (ws_size >= WPB + (F1 + F2) * 4) {
        // Tier MF: MFMA conv1-3 (4 units/block), fp32 conv4-5
        ushort* wp = (ushort*)base;
        float* h1 = (float*)(base + WPB);
        float* h2 = (float*)(base + WPB + F1 * 4);
        float* h3 = (float*)(base + WPB);                      // h1 dead by conv3
        float* h4 = (float*)(base + WPB + F3 * 4);
        float* h5 = (float*)(base + WPB + (F3 + F4) * 4);

        pack_weights<<<3, 64, 0, stream>>>(w1, w2, w3, wp);
        conv4d_mfma<1, 3, 18><<<256 * 15 * 15 / 4, 256, 0, stream>>>(x,  wp,        b1, h1);
        conv4d_mfma<3, 3, 15><<<256 * 12 * 12 / 4, 256, 0, stream>>>(h1, wp + 1024, b2, h2);
        conv4d_mfma<3, 4, 12><<<256 * 9 * 9 / 4,   256, 0, stream>>>(h2, wp + 4096, b3, h3);
        conv4d_relu<4, 5, 9, 4><<<GB(T4n(256)), 256, 0, stream>>>(h3, w4, b4, h4, T4n(256));
        conv4d_relu<5, 5, 6, 3><<<GB(T5n(256)), 256, 0, stream>>>(h4, w5, b5, h5, T5n(256));
        dense_head<<<256, 64, 0, stream>>>(h5, dw1, db1, dw2, db2, outp);
    } else if (ws_size >= (F1 + F2) * 4) {
        // Tier A: all fp32 direct (known-good)
        float* h1 = (float*)base;
        float* h2 = (float*)(base + F1 * 4);
        float* h3 = (float*)base;
        float* h4 = (float*)(base + F3 * 4);
        float* h5 = (float*)(base + (F3 + F4) * 4);
        conv4d_relu<1, 3, 18, 4><<<GB(256 * 15 * 15 * 15), 256, 0, stream>>>(x,  w1, b1, h1, 256 * 15 * 15 * 15);
        conv4d_relu<3, 3, 15, 4><<<GB(256 * 12 * 12 * 12), 256, 0, stream>>>(h1, w2, b2, h2, 256 * 12 * 12 * 12);
        conv4d_relu<3, 4, 12, 4><<<GB(256 * 9 * 9 * 9),    256, 0, stream>>>(h2, w3, b3, h3, 256 * 9 * 9 * 9);
        conv4d_relu<4, 5, 9,  4><<<GB(T4n(256)), 256, 0, stream>>>(h3, w4, b4, h4, T4n(256));
        conv4d_relu<5, 5, 6,  3><<<GB(T5n(256)), 256, 0, stream>>>(h4, w5, b5, h5, T5n(256));
        dense_head<<<256, 64, 0, stream>>>(h5, dw1, db1, dw2, db2, outp);
    } else {
        // Tier D: batch-chunked fp32 (peak ~28.8 MB)
        const int BC = 32, NCHUNK = 8;
        const size_t C1 = (size_t)BC * 3 * 15 * 15 * 15 * 15;
        float* h5 = (float*)base;
        float* hA = (float*)(base + F5 * 4);
        float* hB = (float*)(base + F5 * 4 + C1 * 4);
        for (int c = 0; c < NCHUNK; ++c) {
            const float* xc = x + (size_t)c * BC * 18L * 18 * 18 * 18;
            float* h5c = h5 + (size_t)c * BC * 1280;
            conv4d_relu<1, 3, 18, 4><<<GB(BC * 15 * 15 * 15), 256, 0, stream>>>(xc, w1, b1, hA, BC * 15 * 15 * 15);
            conv4d_relu<3, 3, 15, 4><<<GB(BC * 12 * 12 * 12), 256, 0, stream>>>(hA, w2, b2, hB, BC * 12 * 12 * 12);
            conv4d_relu<3, 4, 12, 4><<<GB(BC * 9 * 9 * 9),    256, 0, stream>>>(hB, w3, b3, hA, BC * 9 * 9 * 9);
            conv4d_relu<4, 5, 9,  4><<<GB(T4n(BC)), 256, 0, stream>>>(hA, w4, b4, hB, T4n(BC));
            conv4d_relu<5, 5, 6,  3><<<GB(T5n(BC)), 256, 0, stream>>>(hB, w5, b5, h5c, T5n(BC));
        }
        dense_head<<<256, 64, 0, stream>>>(h5, dw1, db1, dw2, db2, outp);
    }
}

// Round 8
// 865.558 us; speedup vs baseline: 1.2516x; 1.2516x over previous
//
#include <hip/hip_runtime.h>
#include <hip/hip_bf16.h>

using bf16 = __hip_bfloat16;

typedef short bf16x8 __attribute__((ext_vector_type(8)));
typedef float f32x4  __attribute__((ext_vector_type(4)));

__device__ __forceinline__ f32x4 ld4u(const float* p) {
    f32x4 r;
    __builtin_memcpy(&r, p, 16);   // 4B-aligned dwordx4
    return r;
}

__device__ __forceinline__ bf16x8 pack8(f32x4 a, f32x4 b) {
    union { bf16x8 v; __hip_bfloat162 h2[4]; } u;
    u.h2[0] = __float22bfloat162_rn(make_float2(a.x, a.y));
    u.h2[1] = __float22bfloat162_rn(make_float2(a.z, a.w));
    u.h2[2] = __float22bfloat162_rn(make_float2(b.x, b.y));
    u.h2[3] = __float22bfloat162_rn(make_float2(b.z, b.w));
    return u.v;
}

// Pack W[co][ci][dw][dx][dy][dz] into per-lane MFMA fragment order (validated r5/r6):
// frag elem (lane l, e): i = l&15 = co*4+dy ; k = (l>>4)*8 + e -> (ci,dw,dx,dz) dz-fastest.
__global__ __launch_bounds__(64)
void pack_weights(const float* __restrict__ w1, const float* __restrict__ w2,
                  const float* __restrict__ w3, ushort* __restrict__ wp)
{
    const int L = blockIdx.x, l = threadIdx.x;
    const int CIN  = (L == 0) ? 1 : 3;
    const int COUT = (L == 2) ? 4 : 3;
    const int NSTEP = (L == 0) ? 2 : 6;
    const float* w = (L == 0) ? w1 : (L == 1) ? w2 : w3;
    ushort* dst = wp + ((L == 0) ? 0 : (L == 1) ? 1024 : 4096);

    const int n = l & 15, g = l >> 4;
    const int co = n >> 2, dy = n & 3;
    for (int s = 0; s < NSTEP; ++s)
        for (int e = 0; e < 8; ++e) {
            int k = s * 32 + g * 8 + e;
            int dz = k & 3, dx = (k >> 2) & 3, dw = (k >> 4) & 3, ci = k >> 6;
            float v = 0.f;
            if (co < COUT) v = w[((((co * CIN + ci) * 4 + dw) * 4 + dx) * 4 + dy) * 4 + dz];
            bf16 h = __float2bfloat16(v);
            ushort us; __builtin_memcpy(&us, &h, 2);
            dst[(s * 64 + l) * 8 + e] = us;
        }
}

// Implicit-GEMM 4D conv, MFMA 16x16x32 bf16. Weights = A (rows i = co*4+dy),
// input = B (cols = oz, one tile per iy). Lane n = oz -> lanes read CONTIGUOUS
// overlapping 16B windows (2 cache lines per 16-lane group, was ~15).
// D layout (col=lane&15=oz, row=g*4+reg -> co=g, dy=reg): the dy-reduction is
// fully lane-local: out(oy,oz) = sum_dy acc[oy+dy][dy]. No LDS, no shuffles.
// Block = 4 waves = 4 consecutive units (b, ow, ox).
template<int CIN, int COUT, int SIN>
__global__ __launch_bounds__(256, 2)
void conv4d_mfma(const float* __restrict__ in, const ushort* __restrict__ wp,
                 const float* __restrict__ bias, float* __restrict__ out)
{
    constexpr int SOUT = SIN - 3;
    constexpr int NSTEP = CIN * 2;           // CIN*64 / 32
    constexpr int NT = SIN;                  // one 16-col tile per iy
    constexpr int S2 = SIN * SIN, S3 = SIN * S2, S4 = SIN * S3;

    const int l   = threadIdx.x & 63;
    const int wid = threadIdx.x >> 6;
    const int u   = blockIdx.x * 4 + wid;
    const int ox = u % SOUT, ow = (u / SOUT) % SOUT, b = u / (SOUT * SOUT);
    const int n = l & 15, g = l >> 4;

    // A-operand: weight fragments (persistent, 16B aligned)
    bf16x8 wf[NSTEP];
    #pragma unroll
    for (int s = 0; s < NSTEP; ++s)
        wf[s] = *reinterpret_cast<const bf16x8*>(wp + (s * 64 + l) * 8);

    // lane z-base (clamped so the 16B window stays inside the (iy) row range;
    // lanes n >= SOUT are garbage and masked at the store)
    const int zb = (n < SIN - 4) ? n : (SIN - 4);

    // per-lane slab pointers per k-step: k8 = s*32+g*8 -> (ci,dw,dxb)
    const float* pbase = in + (size_t)b * CIN * S4 + ow * S3 + ox * S2;
    const float* ps[NSTEP];
    #pragma unroll
    for (int s = 0; s < NSTEP; ++s) {
        int k8 = s * 32 + g * 8;
        int dxb = (k8 >> 2) & 3, dw = (k8 >> 4) & 3, ci = k8 >> 6;
        ps[s] = pbase + ci * S4 + dw * S3 + dxb * S2 + zb;
    }

    f32x4 acc[NT];
    #pragma unroll
    for (int t = 0; t < NT; ++t) acc[t] = 0;

    // s-outer / t-inner: NT independent load->pack->mfma streams per step
    #pragma unroll
    for (int s = 0; s < NSTEP; ++s)
        #pragma unroll
        for (int t = 0; t < NT; ++t) {
            f32x4 va = ld4u(ps[s] + t * SIN);
            f32x4 vb = ld4u(ps[s] + S2 + t * SIN);
            acc[t] = __builtin_amdgcn_mfma_f32_16x16x32_bf16(wf[s], pack8(va, vb), acc[t], 0, 0, 0);
        }

    // Lane-local dy-reduce epilogue; 16-lane-contiguous stores
    if (g < COUT && n < SOUT) {
        const float bb = bias[g];
        float* op = out + ((((size_t)(b * COUT + g) * SOUT + ow) * SOUT + ox) * SOUT) * SOUT + n;
        #pragma unroll
        for (int oy = 0; oy < SOUT; ++oy) {
            float v = acc[oy][0] + acc[oy + 1][1] + acc[oy + 2][2] + acc[oy + 3][3] + bb;
            op[oy * SOUT] = v > 0.f ? v : 0.f;
        }
    }
}

// ---- fp32 direct conv (conv4/conv5 + fallback tiers) ----
template<int CIN, int COUT, int SIN, int K>
__global__ __launch_bounds__(256)
void conv4d_relu(const float* __restrict__ in, const float* __restrict__ w,
                 const float* __restrict__ bias, float* __restrict__ out, int total)
{
    constexpr int SOUT = SIN - K + 1;
    constexpr int K4 = K * K * K * K;

    const int t = blockIdx.x * 256 + threadIdx.x;
    if (t >= total) return;
    const int oz = t % SOUT;
    const int ox = (t / SOUT) % SOUT;
    const int ow = (t / (SOUT * SOUT)) % SOUT;
    const int b  = t / (SOUT * SOUT * SOUT);

    float acc[COUT][SOUT];
    #pragma unroll
    for (int co = 0; co < COUT; ++co)
        #pragma unroll
        for (int oy = 0; oy < SOUT; ++oy) acc[co][oy] = 0.f;

    for (int ci = 0; ci < CIN; ++ci)
    for (int dw = 0; dw < K; ++dw)
    for (int dx = 0; dx < K; ++dx) {
        float wv[COUT][K][K];
        const int wbase = ((ci * K + dw) * K + dx) * K * K;
        #pragma unroll
        for (int co = 0; co < COUT; ++co)
            #pragma unroll
            for (int dy = 0; dy < K; ++dy)
                #pragma unroll
                for (int dz = 0; dz < K; ++dz)
                    wv[co][dy][dz] = w[co * (CIN * K4) + wbase + dy * K + dz];

        const float* col = in
            + ((((long)(b * CIN + ci) * SIN + (ow + dw)) * SIN + (ox + dx)) * SIN) * (long)SIN
            + oz;

        #pragma unroll
        for (int iy = 0; iy < SIN; ++iy) {
            float r[K];
            #pragma unroll
            for (int dz = 0; dz < K; ++dz) r[dz] = col[iy * SIN + dz];
            #pragma unroll
            for (int dy = 0; dy < K; ++dy) {
                if (iy - dy >= 0 && iy - dy < SOUT) {
                    #pragma unroll
                    for (int co = 0; co < COUT; ++co)
                        #pragma unroll
                        for (int dz = 0; dz < K; ++dz)
                            acc[co][iy - dy] = fmaf(r[dz], wv[co][dy][dz], acc[co][iy - dy]);
                }
            }
        }
    }

    #pragma unroll
    for (int co = 0; co < COUT; ++co) {
        const float bb = bias[co];
        float* op = out
            + ((((long)(b * COUT + co) * SOUT + ow) * SOUT + ox) * SOUT) * (long)SOUT
            + oz;
        #pragma unroll
        for (int oy = 0; oy < SOUT; ++oy) {
            float v = acc[co][oy] + bb;
            op[oy * SOUT] = v > 0.f ? v : 0.f;
        }
    }
}

// Fused dense1(1280->33, ReLU) + dense2(33->2) + softmax. One wave per batch item.
__global__ __launch_bounds__(64)
void dense_head(const float* __restrict__ h, const float* __restrict__ dw1,
                const float* __restrict__ db1, const float* __restrict__ dw2,
                const float* __restrict__ db2, float* __restrict__ out)
{
    __shared__ float hs[1280];
    __shared__ float gbuf[33];
    const int b = blockIdx.x, l = threadIdx.x;

    for (int i = l; i < 1280; i += 64) hs[i] = h[b * 1280 + i];
    __syncthreads();

    for (int j = 0; j < 33; ++j) {
        float a = 0.f;
        for (int k = l; k < 1280; k += 64) a += hs[k] * dw1[j * 1280 + k];
        #pragma unroll
        for (int off = 32; off > 0; off >>= 1) a += __shfl_down(a, off);
        if (l == 0) { float v = a + db1[j]; gbuf[j] = v > 0.f ? v : 0.f; }
    }
    __syncthreads();

    if (l == 0) {
        float l0 = db2[0], l1 = db2[1];
        for (int j = 0; j < 33; ++j) { l0 += gbuf[j] * dw2[j]; l1 += gbuf[j] * dw2[33 + j]; }
        float m = l0 > l1 ? l0 : l1;
        float e0 = expf(l0 - m), e1 = expf(l1 - m);
        float s = e0 + e1;
        out[b * 2 + 0] = e0 / s;
        out[b * 2 + 1] = e1 / s;
    }
}

extern "C" void kernel_launch(void* const* d_in, const int* in_sizes, int n_in,
                              void* d_out, int out_size, void* d_ws, size_t ws_size,
                              hipStream_t stream)
{
    const float* x   = (const float*)d_in[0];
    const float* w1  = (const float*)d_in[1];  const float* b1  = (const float*)d_in[2];
    const float* w2  = (const float*)d_in[3];  const float* b2  = (const float*)d_in[4];
    const float* w3  = (const float*)d_in[5];  const float* b3  = (const float*)d_in[6];
    const float* w4  = (const float*)d_in[7];  const float* b4  = (const float*)d_in[8];
    const float* w5  = (const float*)d_in[9];  const float* b5  = (const float*)d_in[10];
    const float* dw1 = (const float*)d_in[11]; const float* db1 = (const float*)d_in[12];
    const float* dw2 = (const float*)d_in[13]; const float* db2 = (const float*)d_in[14];
    float* outp = (float*)d_out;

    const size_t F1 = 256L * 3 * 15 * 15 * 15 * 15;  // 38,880,000
    const size_t F2 = 256L * 3 * 12 * 12 * 12 * 12;  // 15,925,248
    const size_t F3 = 256L * 4 * 9 * 9 * 9 * 9;      //  6,718,464
    const size_t F4 = 256L * 5 * 6 * 6 * 6 * 6;      //  1,658,880
    const size_t F5 = 256L * 5 * 4 * 4 * 4 * 4;      //    327,680
    const size_t WPB = 16384;

    char* base = (char*)d_ws;

    auto T4n = [](int nb){ return nb * 6 * 6 * 6; };
    auto T5n = [](int nb){ return nb * 4 * 4 * 4; };
    auto GB  = [](int th){ return (th + 255) / 256; };

    if (ws_size >= WPB + (F1 + F2) * 4) {
        // Tier MF: MFMA conv1-3 (4 units/block), fp32 conv4-5
        ushort* wp = (ushort*)base;
        float* h1 = (float*)(base + WPB);
        float* h2 = (float*)(base + WPB + F1 * 4);
        float* h3 = (float*)(base + WPB);                      // h1 dead by conv3
        float* h4 = (float*)(base + WPB + F3 * 4);
        float* h5 = (float*)(base + WPB + (F3 + F4) * 4);

        pack_weights<<<3, 64, 0, stream>>>(w1, w2, w3, wp);
        conv4d_mfma<1, 3, 18><<<256 * 15 * 15 / 4, 256, 0, stream>>>(x,  wp,        b1, h1);
        conv4d_mfma<3, 3, 15><<<256 * 12 * 12 / 4, 256, 0, stream>>>(h1, wp + 1024, b2, h2);
        conv4d_mfma<3, 4, 12><<<256 * 9 * 9 / 4,   256, 0, stream>>>(h2, wp + 4096, b3, h3);
        conv4d_relu<4, 5, 9, 4><<<GB(T4n(256)), 256, 0, stream>>>(h3, w4, b4, h4, T4n(256));
        conv4d_relu<5, 5, 6, 3><<<GB(T5n(256)), 256, 0, stream>>>(h4, w5, b5, h5, T5n(256));
        dense_head<<<256, 64, 0, stream>>>(h5, dw1, db1, dw2, db2, outp);
    } else if (ws_size >= (F1 + F2) * 4) {
        // Tier A: all fp32 direct (known-good)
        float* h1 = (float*)base;
        float* h2 = (float*)(base + F1 * 4);
        float* h3 = (float*)base;
        float* h4 = (float*)(base + F3 * 4);
        float* h5 = (float*)(base + (F3 + F4) * 4);
        conv4d_relu<1, 3, 18, 4><<<GB(256 * 15 * 15 * 15), 256, 0, stream>>>(x,  w1, b1, h1, 256 * 15 * 15 * 15);
        conv4d_relu<3, 3, 15, 4><<<GB(256 * 12 * 12 * 12), 256, 0, stream>>>(h1, w2, b2, h2, 256 * 12 * 12 * 12);
        conv4d_relu<3, 4, 12, 4><<<GB(256 * 9 * 9 * 9),    256, 0, stream>>>(h2, w3, b3, h3, 256 * 9 * 9 * 9);
        conv4d_relu<4, 5, 9,  4><<<GB(T4n(256)), 256, 0, stream>>>(h3, w4, b4, h4, T4n(256));
        conv4d_relu<5, 5, 6,  3><<<GB(T5n(256)), 256, 0, stream>>>(h4, w5, b5, h5, T5n(256));
        dense_head<<<256, 64, 0, stream>>>(h5, dw1, db1, dw2, db2, outp);
    } else {
        // Tier D: batch-chunked fp32 (peak ~28.8 MB)
        const int BC = 32, NCHUNK = 8;
        const size_t C1 = (size_t)BC * 3 * 15 * 15 * 15 * 15;
        float* h5 = (float*)base;
        float* hA = (float*)(base + F5 * 4);
        float* hB = (float*)(base + F5 * 4 + C1 * 4);
        for (int c = 0; c < NCHUNK; ++c) {
            const float* xc = x + (size_t)c * BC * 18L * 18 * 18 * 18;
            float* h5c = h5 + (size_t)c * BC * 1280;
            conv4d_relu<1, 3, 18, 4><<<GB(BC * 15 * 15 * 15), 256, 0, stream>>>(xc, w1, b1, hA, BC * 15 * 15 * 15);
            conv4d_relu<3, 3, 15, 4><<<GB(BC * 12 * 12 * 12), 256, 0, stream>>>(hA, w2, b2, hB, BC * 12 * 12 * 12);
            conv4d_relu<3, 4, 12, 4><<<GB(BC * 9 * 9 * 9),    256, 0, stream>>>(hB, w3, b3, hA, BC * 9 * 9 * 9);
            conv4d_relu<4, 5, 9,  4><<<GB(T4n(BC)), 256, 0, stream>>>(hA, w4, b4, hB, T4n(BC));
            conv4d_relu<5, 5, 6,  3><<<GB(T5n(BC)), 256, 0, stream>>>(hB, w5, b5, h5c, T5n(BC));
        }
        dense_head<<<256, 64, 0, stream>>>(h5, dw1, db1, dw2, db2, outp);
    }
}